// Round 1
// baseline (873.532 us; speedup 1.0000x reference)
//
#include <hip/hip_runtime.h>
#include <math.h>

// Problem constants (B=1 fixed by reference)
#define NP 9216          // S*S spatial positions
#define DC 256           // channels
#define DN (DC * NP)

#define FEPS 2.220446049250313e-16f

// ---------------- Kernel 1: L2-normalize over channel dim ----------------
// One thread per spatial position (X first NP threads, Y next NP).
// Reads f[d*N+n] coalesced across threads. Writes:
//   X: ws Xf [D,N] (16B-aligned for GEMM float4 loads) + d_out Xf slot
//   Y: ws Yf [D,N] + ws YfT [N,D] (for coalesced column gather later)
__global__ __launch_bounds__(256) void knorm(
    const float* __restrict__ X, const float* __restrict__ Y,
    float* __restrict__ Xf, float* __restrict__ Xf_out,
    float* __restrict__ Yf, float* __restrict__ YfT,
    float* __restrict__ lacc)
{
    int t = blockIdx.x * 256 + threadIdx.x;
    if (t == 0) *lacc = 0.0f;   // zero loss accumulator (d_ws is poisoned each call)

    const float* src = (t < NP) ? X : Y;
    int n = (t < NP) ? t : t - NP;

    float s = 0.0f;
    #pragma unroll 8
    for (int d = 0; d < DC; ++d) {
        float v = src[d * NP + n];
        s = fmaf(v, v, s);
    }
    float inv = 1.0f / (sqrtf(s) + FEPS);

    if (t < NP) {
        #pragma unroll 4
        for (int d = 0; d < DC; ++d) {
            float v = src[d * NP + n] * inv;
            Xf[d * NP + n] = v;
            Xf_out[d * NP + n] = v;
        }
    } else {
        #pragma unroll 4
        for (int d = 0; d < DC; ++d) {
            float v = src[d * NP + n] * inv;
            Yf[d * NP + n] = v;
            YfT[n * DC + d] = v;
        }
    }
}

// ---------------- Kernel 2: fused sim-GEMM + per-row argmax ----------------
// C[n,m] = sum_d Xf[d,n]*Yf[d,m]; never materialized — running (max,idx).
// Tile: BN=96 rows x BM=128 cols, BK=16, 384 threads, 4x8 acc per thread.
// Grid: 96 n-bands x 8 m-chunks = 768 blocks = 3 per CU exactly.
#define BN 96
#define BM 128
#define BK 16
#define NCHUNK 8
#define MCHUNK (NP / NCHUNK)          // 1152
#define MT_PER_CHUNK (MCHUNK / BM)    // 9

__global__ __launch_bounds__(384) void ksim(
    const float* __restrict__ Xf, const float* __restrict__ Yf,
    float* __restrict__ pmax, int* __restrict__ pidx)
{
    __shared__ float As[BK][BN];   // [k][n]
    __shared__ float Bs[BK][BM];   // [k][m]

    const int tid = threadIdx.x;
    const int tx = tid & 15;       // 0..15 -> 8 cols each
    const int ty = tid >> 4;       // 0..23 -> 4 rows each
    const int n0 = blockIdx.x * BN;
    const int chunk = blockIdx.y;
    const int mbase = chunk * MCHUNK;

    float best[4];
    int   bidx[4];
    #pragma unroll
    for (int i = 0; i < 4; ++i) { best[i] = -INFINITY; bidx[i] = 0; }

    for (int mt = 0; mt < MT_PER_CHUNK; ++mt) {
        const int m0 = mbase + mt * BM;
        float acc[4][8];
        #pragma unroll
        for (int i = 0; i < 4; ++i)
            #pragma unroll
            for (int j = 0; j < 8; ++j) acc[i][j] = 0.0f;

        for (int kt = 0; kt < DC / BK; ++kt) {
            // Stage A: 16x96 = 384 float4, one per thread
            {
                int r = tid / 24;
                int c = (tid % 24) * 4;
                *(float4*)(&As[r][c]) =
                    *(const float4*)(&Xf[(kt * BK + r) * NP + n0 + c]);
            }
            // Stage B: 16x128 = 512 float4
            {
                int r = tid >> 5;
                int c = (tid & 31) * 4;
                *(float4*)(&Bs[r][c]) =
                    *(const float4*)(&Yf[(kt * BK + r) * NP + m0 + c]);
                if (tid < 128) {
                    int e = tid + 384;
                    int r2 = e >> 5;
                    int c2 = (e & 31) * 4;
                    *(float4*)(&Bs[r2][c2]) =
                        *(const float4*)(&Yf[(kt * BK + r2) * NP + m0 + c2]);
                }
            }
            __syncthreads();

            #pragma unroll
            for (int k = 0; k < BK; ++k) {
                const float4 a  = *(const float4*)(&As[k][ty * 4]);
                const float4 b0 = *(const float4*)(&Bs[k][tx * 8]);
                const float4 b1 = *(const float4*)(&Bs[k][tx * 8 + 4]);
                const float av[4] = {a.x, a.y, a.z, a.w};
                const float bv[8] = {b0.x, b0.y, b0.z, b0.w,
                                     b1.x, b1.y, b1.z, b1.w};
                #pragma unroll
                for (int i = 0; i < 4; ++i)
                    #pragma unroll
                    for (int j = 0; j < 8; ++j)
                        acc[i][j] = fmaf(av[i], bv[j], acc[i][j]);
            }
            __syncthreads();
        }

        // Fold this m-tile into the running argmax.
        // j ascending == m ascending; strict '>' keeps the FIRST max
        // (matches jnp.argmax tie semantics).
        const int mcol = m0 + tx * 8;
        #pragma unroll
        for (int i = 0; i < 4; ++i)
            #pragma unroll
            for (int j = 0; j < 8; ++j) {
                float v = acc[i][j];
                if (v > best[i]) { best[i] = v; bidx[i] = mcol + j; }
            }
    }

    // Reduce across the 16 tx lanes (same rows). xor<16 stays in group.
    #pragma unroll
    for (int off = 1; off < 16; off <<= 1) {
        #pragma unroll
        for (int i = 0; i < 4; ++i) {
            float ov = __shfl_xor(best[i], off, 64);
            int   oi = __shfl_xor(bidx[i], off, 64);
            if (ov > best[i] || (ov == best[i] && oi < bidx[i])) {
                best[i] = ov; bidx[i] = oi;
            }
        }
    }

    if (tx == 0) {
        #pragma unroll
        for (int i = 0; i < 4; ++i) {
            int row = n0 + ty * 4 + i;
            pmax[row * NCHUNK + chunk] = best[i];
            pidx[row * NCHUNK + chunk] = bidx[i];
        }
    }
}

// ---------------- Kernel 3: reduce chunk partials -> nn_idx ----------------
__global__ __launch_bounds__(256) void kred(
    const float* __restrict__ pmax, const int* __restrict__ pidx,
    int* __restrict__ nn)
{
    int t = blockIdx.x * 256 + threadIdx.x;
    if (t >= NP) return;
    float b = -INFINITY;
    int bi = 0x7fffffff;
    #pragma unroll
    for (int c = 0; c < NCHUNK; ++c) {
        float v = pmax[t * NCHUNK + c];
        int  id = pidx[t * NCHUNK + c];
        if (v > b || (v == b && id < bi)) { b = v; bi = id; }
    }
    nn[t] = bi;
}

// ---------------- Kernel 4: gather Y_sel + fused MSE loss ----------------
// 64n x 64d tile: coalesced read of YfT rows, LDS transpose (pad 65),
// coalesced write of Y_sel in [D,N]; loss accumulated alongside.
__global__ __launch_bounds__(256) void kgather(
    const float* __restrict__ YfT, const int* __restrict__ nn,
    const float* __restrict__ Xf, float* __restrict__ Ysel,
    float* __restrict__ lacc)
{
    __shared__ float tile[64][65];
    __shared__ int   idxs[64];
    __shared__ float wsum[4];

    const int n0 = blockIdx.x * 64;
    const int d0 = blockIdx.y * 64;
    const int tid = threadIdx.x;

    if (tid < 64) idxs[tid] = nn[n0 + tid];
    __syncthreads();

    const int c  = tid & 63;   // lane within wave
    const int r0 = tid >> 6;   // wave id 0..3

    #pragma unroll
    for (int s = 0; s < 16; ++s) {
        int r = s * 4 + r0;    // n-row within tile; whole wave shares r
        tile[r][c] = YfT[(long)idxs[r] * DC + d0 + c];
    }
    __syncthreads();

    float lsum = 0.0f;
    #pragma unroll
    for (int s = 0; s < 16; ++s) {
        int a = s * 4 + r0;            // d-offset within tile
        int d = d0 + a;
        int n = n0 + c;
        float y = tile[c][a];          // stride-65 read: conflict-free
        float x = Xf[(long)d * NP + n];
        float diff = x - y;
        lsum = fmaf(diff, diff, lsum);
        Ysel[(long)d * NP + n] = y;    // coalesced over n
    }

    // block-reduce lsum
    #pragma unroll
    for (int off = 32; off >= 1; off >>= 1)
        lsum += __shfl_xor(lsum, off, 64);
    if ((tid & 63) == 0) wsum[tid >> 6] = lsum;
    __syncthreads();
    if (tid == 0)
        atomicAdd(lacc, wsum[0] + wsum[1] + wsum[2] + wsum[3]);
}

// ---------------- Kernel 5: finalize loss ----------------
__global__ void kfin(const float* __restrict__ lacc, float* __restrict__ out)
{
    out[0] = lacc[0] * (1.0f / (float)DN);
}

extern "C" void kernel_launch(void* const* d_in, const int* in_sizes, int n_in,
                              void* d_out, int out_size, void* d_ws, size_t ws_size,
                              hipStream_t stream)
{
    const float* X = (const float*)d_in[0];   // X_features [1,256,96,96]
    const float* Y = (const float*)d_in[1];   // Y_features [1,256,96,96]
    // d_in[2], d_in[3] (images) are dead code in the reference — unused.

    float* out = (float*)d_out;
    float* Ysel_out = out + 1;          // output 1: Y_sel [1,D,N]
    float* Xf_out   = out + 1 + DN;     // output 2: Xf   [1,D,N]

    // Workspace layout (16B-aligned chunks; d_out slots are 4B-misaligned
    // for float4, so the GEMM reads from these aligned copies).
    float* Xf   = (float*)d_ws;         // DN
    float* Yf   = Xf + DN;              // DN
    float* YfT  = Yf + DN;              // DN  ([N,D] transposed)
    float* pmax = YfT + DN;             // NP*NCHUNK
    int*   pidx = (int*)(pmax + NP * NCHUNK);   // NP*NCHUNK
    int*   nn   = pidx + NP * NCHUNK;   // NP
    float* lacc = (float*)(nn + NP);    // 1

    hipLaunchKernelGGL(knorm, dim3(2 * NP / 256), dim3(256), 0, stream,
                       X, Y, Xf, Xf_out, Yf, YfT, lacc);
    hipLaunchKernelGGL(ksim, dim3(NP / BN, NCHUNK), dim3(384), 0, stream,
                       Xf, Yf, pmax, pidx);
    hipLaunchKernelGGL(kred, dim3((NP + 255) / 256), dim3(256), 0, stream,
                       pmax, pidx, nn);
    hipLaunchKernelGGL(kgather, dim3(NP / 64, DC / 64), dim3(256), 0, stream,
                       YfT, nn, Xf, Ysel_out, lacc);
    hipLaunchKernelGGL(kfin, dim3(1), dim3(1), 0, stream, lacc, out);
}